// Round 7
// baseline (9822.024 us; speedup 1.0000x reference)
//
#include <hip/hip_runtime.h>
#include <stdint.h>

// DCRNN forward, MI355X — one block per batch, zero cross-block communication.
//  - 64 blocks x 512 threads; block b owns batch b entirely (all 256 graph nodes).
//    All state (h0,h1,u) in MFMA-fragment registers; n-mixing via in-LDS
//    transpose only. No atomics, no inter-block barriers, no global state.
//  - LDS: xsT[128][264] bf16 (x/h f-major, 67.5KB) + Hbuf[256][136] bf16
//    (row-major operand / hop outputs, 68KB) + ydec[256] f32 = 138KB -> 1 blk/CU.
//  - prep kernel: A = {S0, 2S0^2-I, S1, 2S1^2-I} bf16 (Chebyshev collapse) and
//    packed weights Wp[o][m*FP+f] (f zero-padded) — both L2-resident afterwards.
//  - Per stage: build xsT+Hbuf (regs->LDS) -> proj(0); 4x {hop GEMM from xsT ->
//    Hbuf; proj(m)} with mfma_f32_16x16x32_bf16 fp32-accum; fused GRU epilogue.
//    Gates write r*h in place; cand stages skip the build. Decoder y in LDS.

typedef short short8 __attribute__((ext_vector_type(8)));
typedef float f32x4 __attribute__((ext_vector_type(4)));

#define DEVI __device__ __forceinline__

DEVI unsigned short f2bf(float x) {
  unsigned int u = __builtin_bit_cast(unsigned int, x);
  u += 0x7FFFu + ((u >> 16) & 1u);  // RNE
  return (unsigned short)(u >> 16);
}

struct KP {
  const float* enc_in;
  const float* sup0; const float* sup1;
  const float* Wsrc[8];
  const float* bias[8];
  const float* prW; const float* prB;
  float* out;
  unsigned short* A;        // [4][256][256] bf16
  unsigned short* Wp[8];    // packed [O][5*FP] bf16
};

// ---------------- prep kernel (512 blocks x 256) ----------------
__global__ void prep(KP p) {
  const int i = blockIdx.x, tid = threadIdx.x;
  {  // A matrices
    const int s = i & 1, r = i >> 1;
    const float* S = s ? p.sup1 : p.sup0;
    float acc = 0.f;
    for (int k = 0; k < 256; ++k) acc = fmaf(S[r * 256 + k], S[k * 256 + tid], acc);
    p.A[(2 * s + 0) * 65536 + r * 256 + tid] = f2bf(S[r * 256 + tid]);
    p.A[(2 * s + 1) * 65536 + r * 256 + tid] = f2bf(2.f * acc - (r == tid ? 1.f : 0.f));
  }
  {  // packed weights: Wp[o][m*FP+f] = W[f,m,o], f zero-padded to FP
    const int gtid = i * 256 + tid;
    const int Fs[8]  = {66, 66, 128, 128, 65, 65, 128, 128};
    const int Os[8]  = {128, 64, 128, 64, 128, 64, 128, 64};
    const int FPs[8] = {96, 96, 128, 128, 96, 96, 128, 128};
    for (int w = 0; w < 8; ++w) {
      const int FPw = FPs[w], KPw = 5 * FPw, tot = Os[w] * KPw;
      for (int e = gtid; e < tot; e += 512 * 256) {
        const int o = e / KPw, k2 = e - o * KPw, m = k2 / FPw, f = k2 - m * FPw;
        p.Wp[w][e] = f2bf((f < Fs[w]) ? p.Wsrc[w][(f * 5 + m) * Os[w] + o] : 0.f);
      }
    }
  }
}

// ---------------- fused diffusion-conv stage (whole batch in one block) ----------------
// MODE 0: gates (O=128, sigmoid; writes r*h into xsT/Hbuf in place, u regs)
// MODE 1: cand  (O=64, tanh; GRU update of hreg)
// MODE 2: MODE1 + final projection (writes out slice and ydec)
template<int IND, int FP, int MODE, bool SKIP_BUILD>
DEVI void dc_stage(int tid, int w, int l15, int l4,
                   const float* __restrict__ xglob,   // IND==2
                   const float* ydec_ld, int ydvalid,  // IND==1 (LDS)
                   f32x4 (&xreg)[2][4],                // IND==64 (= h0)
                   f32x4 (&hreg)[2][4], f32x4 (&ureg)[2][4],
                   const unsigned short* __restrict__ Ab,
                   const unsigned short* __restrict__ Wp,
                   const float* __restrict__ bias,
                   const float* __restrict__ projW, const float* __restrict__ projB,
                   float* outp, float* ydec_st,
                   unsigned short* xsT, unsigned short* Hbuf)
{
  constexpr int F = IND + 64;
  constexpr int O = (MODE == 0) ? 128 : 64;
  constexpr int KPW = 5 * FP;
  constexpr int XS = 264;            // xsT row stride
  constexpr int HS = 136;            // Hbuf row stride
  constexpr int NFT = FP / 16;
  constexpr int NOT_ = O / 16;
  constexpr int KPJ = FP / 32;

  if (!SKIP_BUILD) {
    __syncthreads();                 // previous stage's Hbuf/xsT readers done
    // h-part from registers: thread holds h[n = (w+half*8)*16 + l4*4+j][f = ft*16+l15]
#pragma unroll
    for (int half = 0; half < 2; ++half)
#pragma unroll
      for (int ft = 0; ft < 4; ++ft) {
        const int f = IND + ft * 16 + l15;
#pragma unroll
        for (int j = 0; j < 4; ++j) {
          const int n = (w + half * 8) * 16 + l4 * 4 + j;
          const unsigned short s = f2bf(hreg[half][ft][j]);
          xsT[f * XS + n] = s;
          Hbuf[n * HS + f] = s;
        }
      }
    if (IND == 64) {                 // x-part = h0 registers
#pragma unroll
      for (int half = 0; half < 2; ++half)
#pragma unroll
        for (int ft = 0; ft < 4; ++ft) {
          const int f = ft * 16 + l15;
#pragma unroll
          for (int j = 0; j < 4; ++j) {
            const int n = (w + half * 8) * 16 + l4 * 4 + j;
            const unsigned short s = f2bf(xreg[half][ft][j]);
            xsT[f * XS + n] = s;
            Hbuf[n * HS + f] = s;
          }
        }
    } else if (IND == 2) {
      const float v = xglob[tid];    // 512 floats exactly
      const int n = tid >> 1, f = tid & 1;
      const unsigned short s = f2bf(v);
      xsT[f * XS + n] = s;
      Hbuf[n * HS + f] = s;
    } else {                          // IND == 1: decoder feedback from LDS
      if (tid < 256) {
        const float v = ydvalid ? ydec_ld[tid] : 0.f;
        const unsigned short s = f2bf(v);
        xsT[tid] = s;
        Hbuf[tid * HS] = s;
      }
    }
    if (F < FP) {                     // zero pads: makes hop outputs into pads 0
      for (int e = tid; e < (FP - F) * 256; e += 512) {
        const int f = F + (e >> 8), n = e & 255;
        xsT[f * XS + n] = 0;
        Hbuf[n * HS + f] = 0;
      }
    }
    __syncthreads();
  }

  f32x4 pacc[2][NOT_];
#pragma unroll
  for (int h2 = 0; h2 < 2; ++h2)
#pragma unroll
    for (int oi = 0; oi < NOT_; ++oi) pacc[h2][oi] = 0.f;

  auto proj = [&](int m) {
#pragma unroll
    for (int kk = 0; kk < KPJ; ++kk) {
      const int k0 = kk * 32;
      short8 af[2];
#pragma unroll
      for (int half = 0; half < 2; ++half)
        af[half] = *reinterpret_cast<const short8*>(&Hbuf[((w + half * 8) * 16 + l15) * HS + k0 + l4 * 8]);
#pragma unroll
      for (int ot = 0; ot < NOT_; ++ot) {
        short8 bf = *reinterpret_cast<const short8*>(&Wp[(ot * 16 + l15) * KPW + m * FP + k0 + l4 * 8]);
#pragma unroll
        for (int half = 0; half < 2; ++half)
          pacc[half][ot] = __builtin_amdgcn_mfma_f32_16x16x32_bf16(af[half], bf, pacc[half][ot], 0, 0, 0);
      }
    }
  };

  proj(0);  // identity slice
#pragma unroll 1
  for (int m = 0; m < 4; ++m) {
    const unsigned short* __restrict__ Am = Ab + m * 65536;
    __syncthreads();                 // proj(m-1) Hbuf readers done
#pragma unroll 1
    for (int half = 0; half < 2; ++half) {
      f32x4 hacc[NFT];
#pragma unroll
      for (int fi = 0; fi < NFT; ++fi) hacc[fi] = 0.f;
#pragma unroll
      for (int kk = 0; kk < 8; ++kk) {
        const int k0 = kk * 32;
        short8 af = *reinterpret_cast<const short8*>(&Am[((w + half * 8) * 16 + l15) * 256 + k0 + l4 * 8]);
#pragma unroll
        for (int fi = 0; fi < NFT; ++fi) {
          short8 bf = *reinterpret_cast<const short8*>(&xsT[(fi * 16 + l15) * XS + k0 + l4 * 8]);
          hacc[fi] = __builtin_amdgcn_mfma_f32_16x16x32_bf16(af, bf, hacc[fi], 0, 0, 0);
        }
      }
#pragma unroll
      for (int fi = 0; fi < NFT; ++fi)
#pragma unroll
        for (int j = 0; j < 4; ++j)
          Hbuf[((w + half * 8) * 16 + l4 * 4 + j) * HS + fi * 16 + l15] = f2bf(hacc[fi][j]);
    }
    __syncthreads();
    proj(m + 1);
  }

  // ---- epilogue ----
  if (MODE == 0) {
    f32x4 rh[2][4];
#pragma unroll
    for (int half = 0; half < 2; ++half)
#pragma unroll
      for (int ft = 0; ft < 4; ++ft) {
        const float br = bias[ft * 16 + l15];
        const float bu = bias[64 + ft * 16 + l15];
#pragma unroll
        for (int j = 0; j < 4; ++j) {
          const float r = 1.f / (1.f + __expf(-(pacc[half][ft][j] + br)));
          ureg[half][ft][j] = 1.f / (1.f + __expf(-(pacc[half][ft + 4][j] + bu)));
          rh[half][ft][j] = r * hreg[half][ft][j];
        }
      }
    __syncthreads();                 // proj(4) readers done
    // xs' = [x, r*h]: rewrite h-part, restore Hbuf x-cols (hop outputs clobbered them)
#pragma unroll
    for (int half = 0; half < 2; ++half)
#pragma unroll
      for (int ft = 0; ft < 4; ++ft) {
        const int f = IND + ft * 16 + l15;
#pragma unroll
        for (int j = 0; j < 4; ++j) {
          const int n = (w + half * 8) * 16 + l4 * 4 + j;
          const unsigned short s = f2bf(rh[half][ft][j]);
          xsT[f * XS + n] = s;
          Hbuf[n * HS + f] = s;
        }
      }
    if (IND == 64) {
#pragma unroll
      for (int half = 0; half < 2; ++half)
#pragma unroll
        for (int ft = 0; ft < 4; ++ft) {
          const int f = ft * 16 + l15;
#pragma unroll
          for (int j = 0; j < 4; ++j) {
            const int n = (w + half * 8) * 16 + l4 * 4 + j;
            Hbuf[n * HS + f] = f2bf(xreg[half][ft][j]);
          }
        }
    } else if (IND == 2) {
      Hbuf[(tid >> 1) * HS + (tid & 1)] = f2bf(xglob[tid]);
    } else {
      if (tid < 256) Hbuf[tid * HS] = ydvalid ? f2bf(ydec_ld[tid]) : (unsigned short)0;
    }
    // pad cols [F,FP) hold hop(4) outputs which are exactly 0 (xsT pads were 0)
    __syncthreads();
  } else {
#pragma unroll
    for (int half = 0; half < 2; ++half)
#pragma unroll
      for (int ft = 0; ft < 4; ++ft) {
        const float bc = bias[ft * 16 + l15];
#pragma unroll
        for (int j = 0; j < 4; ++j) {
          const float ex = __expf(2.f * (pacc[half][ft][j] + bc));
          const float c = 1.f - 2.f / (ex + 1.f);   // tanh
          hreg[half][ft][j] = ureg[half][ft][j] * hreg[half][ft][j]
                            + (1.f - ureg[half][ft][j]) * c;
        }
      }
    if (MODE == 2) {
      __syncthreads();               // proj(4) readers done before fp32 overlay
      float* hrow = reinterpret_cast<float*>(Hbuf);   // [256][68] fp32 (68*4 == 136*2)
#pragma unroll
      for (int half = 0; half < 2; ++half)
#pragma unroll
        for (int ft = 0; ft < 4; ++ft)
#pragma unroll
          for (int j = 0; j < 4; ++j)
            hrow[((w + half * 8) * 16 + l4 * 4 + j) * 68 + ft * 16 + l15] = hreg[half][ft][j];
      __syncthreads();
      if (tid < 256) {
        float acc = projB[0];
        const float* hr = hrow + tid * 68;
#pragma unroll
        for (int f = 0; f < 64; ++f) acc = fmaf(hr[f], projW[f], acc);
        outp[tid] = acc;             // global out slice
        ydec_st[tid] = acc;          // LDS feedback for next t
      }
    }
  }
}

// ---------------- main kernel (64 blocks x 512 threads, 1 block = 1 batch) ----------------
__launch_bounds__(512, 2)
__global__ void dcrnn_main(KP p) {
  __shared__ __align__(16) unsigned short xsT[128 * 264];   // 67584 B
  __shared__ __align__(16) unsigned short Hbuf[256 * 136];  // 69632 B
  __shared__ __align__(16) float ydec[256];                 // 1024 B -> 138240 total
  const int tid = threadIdx.x;
  const int w = tid >> 6, ln = tid & 63, l15 = ln & 15, l4 = ln >> 4;
  const int b = (int)blockIdx.x;

  f32x4 h0[2][4], h1[2][4], u[2][4];
#pragma unroll
  for (int half = 0; half < 2; ++half)
#pragma unroll
    for (int ft = 0; ft < 4; ++ft) { h0[half][ft] = 0.f; h1[half][ft] = 0.f; u[half][ft] = 0.f; }

  // ---- encoder ----
#pragma unroll 1
  for (int t = 0; t < 12; ++t) {
    const float* x = p.enc_in + (b * 12 + t) * 512;
    dc_stage<2, 96, 0, false>(tid, w, l15, l4, x, nullptr, 0, h0, h0, u,
                              p.A, p.Wp[0], p.bias[0], nullptr, nullptr, nullptr, nullptr, xsT, Hbuf);
    dc_stage<2, 96, 1, true >(tid, w, l15, l4, x, nullptr, 0, h0, h0, u,
                              p.A, p.Wp[1], p.bias[1], nullptr, nullptr, nullptr, nullptr, xsT, Hbuf);
    dc_stage<64, 128, 0, false>(tid, w, l15, l4, nullptr, nullptr, 0, h0, h1, u,
                                p.A, p.Wp[2], p.bias[2], nullptr, nullptr, nullptr, nullptr, xsT, Hbuf);
    dc_stage<64, 128, 1, true >(tid, w, l15, l4, nullptr, nullptr, 0, h0, h1, u,
                                p.A, p.Wp[3], p.bias[3], nullptr, nullptr, nullptr, nullptr, xsT, Hbuf);
  }

  // ---- decoder ----
#pragma unroll 1
  for (int t = 0; t < 12; ++t) {
    dc_stage<1, 96, 0, false>(tid, w, l15, l4, nullptr, ydec, t > 0, h0, h0, u,
                              p.A, p.Wp[4], p.bias[4], nullptr, nullptr, nullptr, nullptr, xsT, Hbuf);
    dc_stage<1, 96, 1, true >(tid, w, l15, l4, nullptr, ydec, t > 0, h0, h0, u,
                              p.A, p.Wp[5], p.bias[5], nullptr, nullptr, nullptr, nullptr, xsT, Hbuf);
    dc_stage<64, 128, 0, false>(tid, w, l15, l4, nullptr, nullptr, 0, h0, h1, u,
                                p.A, p.Wp[6], p.bias[6], nullptr, nullptr, nullptr, nullptr, xsT, Hbuf);
    dc_stage<64, 128, 2, true >(tid, w, l15, l4, nullptr, nullptr, 0, h0, h1, u,
                                p.A, p.Wp[7], p.bias[7], p.prW, p.prB,
                                p.out + (b * 12 + t) * 256, ydec, xsT, Hbuf);
  }
}

// ---------------- host ----------------
extern "C" void kernel_launch(void* const* d_in, const int* in_sizes, int n_in,
                              void* d_out, int out_size, void* d_ws, size_t ws_size,
                              hipStream_t stream)
{
  (void)in_sizes; (void)n_in; (void)out_size; (void)ws_size;
  KP p;
  p.enc_in = (const float*)d_in[0];
  p.sup0 = (const float*)d_in[2];
  p.sup1 = (const float*)d_in[3];
  p.Wsrc[0] = (const float*)d_in[4];  p.bias[0] = (const float*)d_in[5];
  p.Wsrc[1] = (const float*)d_in[6];  p.bias[1] = (const float*)d_in[7];
  p.Wsrc[2] = (const float*)d_in[8];  p.bias[2] = (const float*)d_in[9];
  p.Wsrc[3] = (const float*)d_in[10]; p.bias[3] = (const float*)d_in[11];
  p.Wsrc[4] = (const float*)d_in[12]; p.bias[4] = (const float*)d_in[13];
  p.Wsrc[5] = (const float*)d_in[14]; p.bias[5] = (const float*)d_in[15];
  p.Wsrc[6] = (const float*)d_in[16]; p.bias[6] = (const float*)d_in[17];
  p.Wsrc[7] = (const float*)d_in[18]; p.bias[7] = (const float*)d_in[19];
  p.prW = (const float*)d_in[20];
  p.prB = (const float*)d_in[21];
  p.out = (float*)d_out;

  char* ws = (char*)d_ws;
  size_t off = 0;
  auto carve = [&](size_t bytes) -> char* {
    char* qp = ws + off;
    off += (bytes + 255) & ~(size_t)255;
    return qp;
  };
  p.A = (unsigned short*)carve(4 * 65536 * 2);
  p.Wp[0] = (unsigned short*)carve(128 * 480 * 2);
  p.Wp[1] = (unsigned short*)carve(64 * 480 * 2);
  p.Wp[2] = (unsigned short*)carve(128 * 640 * 2);
  p.Wp[3] = (unsigned short*)carve(64 * 640 * 2);
  p.Wp[4] = (unsigned short*)carve(128 * 480 * 2);
  p.Wp[5] = (unsigned short*)carve(64 * 480 * 2);
  p.Wp[6] = (unsigned short*)carve(128 * 640 * 2);
  p.Wp[7] = (unsigned short*)carve(64 * 640 * 2);

  prep<<<dim3(512), dim3(256), 0, stream>>>(p);
  dcrnn_main<<<dim3(64), dim3(512), 0, stream>>>(p);
}

// Round 8
// 2736.323 us; speedup vs baseline: 3.5895x; 3.5895x over previous
//
#include <hip/hip_runtime.h>
#include <stdint.h>

// DCRNN forward, MI355X — persistent plain-launch, L3-coherent state exchange.
//  R8 = R5 (2305us, passing) + (1) 16B sc0/sc1 asm loads for state staging
//  (was 8B atomic loads), (2) Hbuf double-buffer (4 fewer syncs/stage).
//  - prep: A = {S0, 2S0^2-I, S1, 2S1^2-I} bf16, packed weights, zero hidden, reset barriers.
//  - main: 256 blocks x 512 threads = 64 batches x 4 row-quadrants; 102400 B LDS
//    forces 1 block/CU -> all 256 blocks co-resident. Per-batch 4-block barrier:
//    relaxed agent atomics (no fences -> no L2 wb/inv).
//  - Cross-block state (H/RH/XD): sc0+sc1 accesses (L1/L2-bypass, L3-coherent,
//    XCD-placement-independent). Read-only A/Wp/bias normal cached loads.
//  - h/u state in MFMA-fragment registers across all 48 cells.

typedef short short8 __attribute__((ext_vector_type(8)));
typedef float f32x4 __attribute__((ext_vector_type(4)));
typedef unsigned short ushort4v __attribute__((ext_vector_type(4)));
typedef unsigned long long u64;
typedef int i32x4 __attribute__((ext_vector_type(4)));

#define DEVI __device__ __forceinline__

DEVI unsigned short f2bf(float x) {
  unsigned int u = __builtin_bit_cast(unsigned int, x);
  u += 0x7FFFu + ((u >> 16) & 1u);  // RNE
  return (unsigned short)(u >> 16);
}
DEVI void ast(u64* p, u64 v) { __hip_atomic_store(p, v, __ATOMIC_RELAXED, __HIP_MEMORY_SCOPE_AGENT); }
DEVI float aldf(const float* p) { return __hip_atomic_load(p, __ATOMIC_RELAXED, __HIP_MEMORY_SCOPE_AGENT); }
DEVI void astf(float* p, float v) { __hip_atomic_store(p, v, __ATOMIC_RELAXED, __HIP_MEMORY_SCOPE_AGENT); }

// 16B L3-coherent load: bypass L1 (sc0) and L2 (sc1); served by memory-side L3.
DEVI i32x4 ldg_sc01(const void* p) {
  i32x4 r;
  asm volatile("global_load_dwordx4 %0, %1, off sc0 sc1" : "=v"(r) : "v"(p));
  return r;
}

struct KP {
  const float* enc_in;
  const float* sup0; const float* sup1;
  const float* Wsrc[8];
  const float* bias[8];
  const float* prW; const float* prB;
  float* out;
  unsigned short* A;        // [4][256][256] bf16
  unsigned short* Wp[8];    // packed [O][5*FP] bf16
  unsigned short* H0[2];    // [64 b][64 f][256 n] bf16 rows, ping-pong
  unsigned short* H1[2];
  unsigned short* RH0;      // r*h rows
  unsigned short* RH1;
  float* XD;                // [64][256] decoder feedback
  unsigned* ctr;            // 64 per-batch counters, 256B apart
};

// ---------------- prep kernel (512 blocks x 256) ----------------
__global__ void prep(KP p) {
  const int i = blockIdx.x, tid = threadIdx.x;
  {  // A matrices
    const int s = i & 1, r = i >> 1;
    const float* S = s ? p.sup1 : p.sup0;
    float acc = 0.f;
    for (int k = 0; k < 256; ++k) acc = fmaf(S[r * 256 + k], S[k * 256 + tid], acc);
    p.A[(2 * s + 0) * 65536 + r * 256 + tid] = f2bf(S[r * 256 + tid]);
    p.A[(2 * s + 1) * 65536 + r * 256 + tid] = f2bf(2.f * acc - (r == tid ? 1.f : 0.f));
  }
  {  // packed weights: Wp[o][m*FP+f] = W[f,m,o], f zero-padded to FP
    const int gtid = i * 256 + tid;
    const int Fs[8]  = {66, 66, 128, 128, 65, 65, 128, 128};
    const int Os[8]  = {128, 64, 128, 64, 128, 64, 128, 64};
    const int FPs[8] = {96, 96, 128, 128, 96, 96, 128, 128};
    for (int w = 0; w < 8; ++w) {
      const int FPw = FPs[w], KPw = 5 * FPw, tot = Os[w] * KPw;
      for (int e = gtid; e < tot; e += 512 * 256) {
        const int o = e / KPw, k2 = e - o * KPw, m = k2 / FPw, f = k2 - m * FPw;
        p.Wp[w][e] = f2bf((f < Fs[w]) ? p.Wsrc[w][(f * 5 + m) * Os[w] + o] : 0.f);
      }
    }
  }
  {  // zero initial hidden via agent-scope stores (visible to main's sc0/sc1 loads)
    const int gtid = i * 256 + tid;
    u64* z0 = (u64*)p.H0[0];
    u64* z1 = (u64*)p.H1[0];
    ast(z0 + 2 * gtid, 0); ast(z0 + 2 * gtid + 1, 0);
    ast(z1 + 2 * gtid, 0); ast(z1 + 2 * gtid + 1, 0);
  }
  if (i == 0 && tid < 64)
    __hip_atomic_store(p.ctr + tid * 64, 0u, __ATOMIC_RELAXED, __HIP_MEMORY_SCOPE_AGENT);
}

// ---------------- fused diffusion-conv stage ----------------
// MODE 0: gates (O=128, sigmoid; writes RH rows, u regs)
// MODE 1: cand  (O=64, tanh; GRU update of hreg; writes H rows)
// MODE 2: MODE1 + final projection (writes out slice and XD)
template<int IND, int FP, int MODE>
DEVI void dc_stage(int b, int n0, int tid,
                   const float* xf32,             // IND<=2 x input (IND==1 via sc1)
                   const unsigned short* xbf,     // IND==64 bf16 rows [64][256]
                   const unsigned short* hrows,   // bf16 rows [64][256] (h or r*h)
                   const unsigned short* Amats,
                   const unsigned short* Wp, const float* bias,
                   f32x4 (&hreg)[2], f32x4 (&ureg)[2],
                   unsigned short* grows,         // output rows (RH or Hnew)
                   const float* projW, const float* projB,
                   float* outp, float* xdout,
                   unsigned short* xsT, unsigned short* Hbuf)
{
  constexpr int F = IND + 64;
  constexpr int O = (MODE == 0) ? 128 : 64;
  constexpr int KPW = 5 * FP;
  constexpr int XS = 264;            // xsT row stride (bf16 elems)
  constexpr int HS = 136;            // Hbuf row stride
  constexpr int HB = 64 * HS;        // one Hbuf buffer
  constexpr int NFT = FP / 16;
  constexpr int NOT_ = O / 16;
  constexpr int FT_W = (NFT + 3) / 4;
  constexpr int OT_W = (NOT_ + 3) / 4;

  const int wv8 = tid >> 6, ln = tid & 63;
  const int l15 = ln & 15, l4 = ln >> 4;
  const int wr = wv8 & 1, wc = wv8 >> 1;   // row-half / tile-column quarter
  const int r0 = wr * 32;

  // ---- build xsT [f][n]: state rows via 16B sc0/sc1 loads (all in flight) ----
  // 64 rows x 256 cols bf16 = 2048 x 16B chunks; chunk g: row = g>>5, c = g&31.
  {
    i32x4 va[4];
#pragma unroll
    for (int it = 0; it < 4; ++it)
      va[it] = ldg_sc01(reinterpret_cast<const char*>(hrows) + (tid + it * 512) * 16);
    i32x4 vb[4];
    if (IND == 64) {
#pragma unroll
      for (int it = 0; it < 4; ++it)
        vb[it] = ldg_sc01(reinterpret_cast<const char*>(xbf) + (tid + it * 512) * 16);
    }
    asm volatile("s_waitcnt vmcnt(0)" ::: "memory");
#pragma unroll
    for (int it = 0; it < 4; ++it) {
      const int g = tid + it * 512, row = g >> 5, c = g & 31;
      *reinterpret_cast<i32x4*>(&xsT[(IND + row) * XS + c * 8]) = va[it];
    }
    if (IND == 64) {
#pragma unroll
      for (int it = 0; it < 4; ++it) {
        const int g = tid + it * 512, row = g >> 5, c = g & 31;
        *reinterpret_cast<i32x4*>(&xsT[row * XS + c * 8]) = vb[it];
      }
    }
  }
  if (IND == 2) {
    const float v = xf32[tid];               // read-only input, cached
    xsT[(tid & 1) * XS + (tid >> 1)] = f2bf(v);
  } else if (IND == 1) {                     // decoder feedback via sc1
    if (tid < 256) xsT[tid] = xf32 ? f2bf(aldf(xf32 + tid)) : (unsigned short)0;
  }
  if (F < FP) {
    for (int e = tid; e < (FP - F) * 256; e += 512)
      xsT[(F + (e >> 8)) * XS + (e & 255)] = 0;
  }
  __syncthreads();
  // ---- Hbuf buf0 = transpose of xsT columns [n0,n0+64): [nl][f] ----
#pragma unroll
  for (int it = 0; it < FP / 8; ++it) {
    const int e = tid + it * 512, f = e >> 6, nl = e & 63;
    Hbuf[nl * HS + f] = xsT[f * XS + n0 + nl];
  }
  __syncthreads();

  f32x4 pacc[2][OT_W];
#pragma unroll
  for (int rt = 0; rt < 2; ++rt)
#pragma unroll
    for (int oi = 0; oi < OT_W; ++oi) pacc[rt][oi] = 0.f;

  auto proj_step = [&](int m, const unsigned short* hb) {
#pragma unroll
    for (int k0 = 0; k0 < FP; k0 += 32) {
      short8 af[2];
#pragma unroll
      for (int rt = 0; rt < 2; ++rt)
        af[rt] = *reinterpret_cast<const short8*>(&hb[(r0 + rt * 16 + l15) * HS + k0 + l4 * 8]);
#pragma unroll
      for (int oi = 0; oi < OT_W; ++oi) {
        const int ot = wc + 4 * oi;
        if (ot < NOT_) {
          short8 bf = *reinterpret_cast<const short8*>(&Wp[(ot * 16 + l15) * KPW + m * FP + k0 + l4 * 8]);
#pragma unroll
          for (int rt = 0; rt < 2; ++rt)
            pacc[rt][oi] = __builtin_amdgcn_mfma_f32_16x16x32_bf16(af[rt], bf, pacc[rt][oi], 0, 0, 0);
        }
      }
    }
  };

  proj_step(0, Hbuf);  // identity slice (buf0)

  for (int mi = 0; mi < 4; ++mi) {
    const unsigned short* Am = Amats + mi * 65536;
    f32x4 hacc[2][FT_W];
#pragma unroll
    for (int rt = 0; rt < 2; ++rt)
#pragma unroll
      for (int fi = 0; fi < FT_W; ++fi) hacc[rt][fi] = 0.f;

#pragma unroll
    for (int k0 = 0; k0 < 256; k0 += 32) {
      short8 af[2];
#pragma unroll
      for (int rt = 0; rt < 2; ++rt)
        af[rt] = *reinterpret_cast<const short8*>(&Am[(n0 + r0 + rt * 16 + l15) * 256 + k0 + l4 * 8]);
#pragma unroll
      for (int fi = 0; fi < FT_W; ++fi) {
        const int ft = wc + 4 * fi;
        if (ft < NFT) {
          short8 bf = *reinterpret_cast<const short8*>(&xsT[(ft * 16 + l15) * XS + k0 + l4 * 8]);
#pragma unroll
          for (int rt = 0; rt < 2; ++rt)
            hacc[rt][fi] = __builtin_amdgcn_mfma_f32_16x16x32_bf16(af[rt], bf, hacc[rt][fi], 0, 0, 0);
        }
      }
    }
    // double-buffer: hop mi writes buf[(mi+1)&1]; proj(mi) read buf[mi&1] (disjoint)
    unsigned short* dst = Hbuf + ((mi + 1) & 1) * HB;
#pragma unroll
    for (int fi = 0; fi < FT_W; ++fi) {
      const int ft = wc + 4 * fi;
      if (ft < NFT) {
#pragma unroll
        for (int rt = 0; rt < 2; ++rt)
#pragma unroll
          for (int j = 0; j < 4; ++j)
            dst[(r0 + rt * 16 + l4 * 4 + j) * HS + ft * 16 + l15] = f2bf(hacc[rt][fi][j]);
      }
    }
    __syncthreads();
    proj_step(mi + 1, dst);
  }

  // ---- epilogue ----
  if (MODE == 0) {
    const float br = bias[wc * 16 + l15];
    const float bu = bias[64 + wc * 16 + l15];
#pragma unroll
    for (int rt = 0; rt < 2; ++rt) {
      f32x4 uu;
      ushort4v pk;
#pragma unroll
      for (int jj = 0; jj < 4; ++jj) {
        const float r = 1.f / (1.f + __expf(-(pacc[rt][0][jj] + br)));
        uu[jj] = 1.f / (1.f + __expf(-(pacc[rt][1][jj] + bu)));
        pk[jj] = f2bf(r * hreg[rt][jj]);
      }
      ureg[rt] = uu;
      ast((u64*)(grows + (wc * 16 + l15) * 256 + n0 + r0 + rt * 16 + l4 * 4),
          __builtin_bit_cast(u64, pk));
    }
  } else {
    float* hrow = reinterpret_cast<float*>(Hbuf);   // [64][68] fp32 overlay of buf0
    if (MODE == 2) __syncthreads();                 // proj(4) readers (buf0) done
    const float bc = bias[wc * 16 + l15];
#pragma unroll
    for (int rt = 0; rt < 2; ++rt) {
      f32x4 hn;
      ushort4v pk;
#pragma unroll
      for (int jj = 0; jj < 4; ++jj) {
        const float ex = __expf(2.f * (pacc[rt][0][jj] + bc));
        const float c = 1.f - 2.f / (ex + 1.f);     // tanh
        hn[jj] = ureg[rt][jj] * hreg[rt][jj] + (1.f - ureg[rt][jj]) * c;
        pk[jj] = f2bf(hn[jj]);
      }
      hreg[rt] = hn;
      ast((u64*)(grows + (wc * 16 + l15) * 256 + n0 + r0 + rt * 16 + l4 * 4),
          __builtin_bit_cast(u64, pk));
      if (MODE == 2) {
#pragma unroll
        for (int jj = 0; jj < 4; ++jj)
          hrow[(r0 + rt * 16 + l4 * 4 + jj) * 68 + wc * 16 + l15] = hn[jj];
      }
    }
    if (MODE == 2) {
      __syncthreads();
      if (tid < 64) {
        float acc = projB[0];
        const float* hr = hrow + tid * 68;
#pragma unroll
        for (int hid = 0; hid < 64; ++hid) acc = fmaf(hr[hid], projW[hid], acc);
        outp[b * 3072 + n0 + tid] = acc;            // normal store (host-read only)
        astf(xdout + b * 256 + n0 + tid, acc);      // sc1 (cross-block feedback)
      }
    }
  }
}

// ---------------- persistent main kernel (256 blocks x 512) ----------------
__launch_bounds__(512, 2)
__global__ void dcrnn_main(KP p) {
  __shared__ __align__(16) unsigned short xsT[128 * 264];     // 67584 B
  __shared__ __align__(16) unsigned short Hbuf[2 * 64 * 136]; // 34816 B -> 102400, 1 blk/CU
  const int tid = threadIdx.x;
  const int i = (int)blockIdx.x;
  const int q = (i >> 3) & 3;
  const int b = (i & 7) + 8 * (i >> 5);   // batch's 4 blocks share blockIdx%8
  const int n0 = q * 64;

  unsigned* ctr = p.ctr + b * 64;
  unsigned st = 0;
  auto BAR = [&]() {
    ++st;
    asm volatile("s_waitcnt vmcnt(0)" ::: "memory");  // state stores at L3
    __syncthreads();
    if (tid == 0) {
      __hip_atomic_fetch_add(ctr, 1u, __ATOMIC_RELAXED, __HIP_MEMORY_SCOPE_AGENT);
      const unsigned target = st * 4u;
      while (__hip_atomic_load(ctr, __ATOMIC_RELAXED, __HIP_MEMORY_SCOPE_AGENT) < target)
        __builtin_amdgcn_s_sleep(2);
    }
    __syncthreads();
  };

  f32x4 h0[2], h1[2], u[2];
#pragma unroll
  for (int rt = 0; rt < 2; ++rt) { h0[rt] = 0.f; h1[rt] = 0.f; u[rt] = 0.f; }
  int c0 = 0, c1 = 0;

  // ---- encoder ----
  for (int t = 0; t < 12; ++t) {
    const float* x0 = p.enc_in + (b * 12 + t) * 512;
    dc_stage<2, 96, 0>(b, n0, tid, x0, nullptr, p.H0[c0] + b * 16384, p.A, p.Wp[0], p.bias[0],
                       h0, u, p.RH0 + b * 16384, nullptr, nullptr, nullptr, nullptr, xsT, Hbuf);
    BAR();
    dc_stage<2, 96, 1>(b, n0, tid, x0, nullptr, p.RH0 + b * 16384, p.A, p.Wp[1], p.bias[1],
                       h0, u, p.H0[c0 ^ 1] + b * 16384, nullptr, nullptr, nullptr, nullptr, xsT, Hbuf);
    BAR(); c0 ^= 1;
    dc_stage<64, 128, 0>(b, n0, tid, nullptr, p.H0[c0] + b * 16384, p.H1[c1] + b * 16384, p.A, p.Wp[2], p.bias[2],
                         h1, u, p.RH1 + b * 16384, nullptr, nullptr, nullptr, nullptr, xsT, Hbuf);
    BAR();
    dc_stage<64, 128, 1>(b, n0, tid, nullptr, p.H0[c0] + b * 16384, p.RH1 + b * 16384, p.A, p.Wp[3], p.bias[3],
                         h1, u, p.H1[c1 ^ 1] + b * 16384, nullptr, nullptr, nullptr, nullptr, xsT, Hbuf);
    BAR(); c1 ^= 1;
  }

  // ---- decoder ----
  for (int t = 0; t < 12; ++t) {
    const float* xd = t ? (p.XD + b * 256) : nullptr;
    dc_stage<1, 96, 0>(b, n0, tid, xd, nullptr, p.H0[c0] + b * 16384, p.A, p.Wp[4], p.bias[4],
                       h0, u, p.RH0 + b * 16384, nullptr, nullptr, nullptr, nullptr, xsT, Hbuf);
    BAR();
    dc_stage<1, 96, 1>(b, n0, tid, xd, nullptr, p.RH0 + b * 16384, p.A, p.Wp[5], p.bias[5],
                       h0, u, p.H0[c0 ^ 1] + b * 16384, nullptr, nullptr, nullptr, nullptr, xsT, Hbuf);
    BAR(); c0 ^= 1;
    dc_stage<64, 128, 0>(b, n0, tid, nullptr, p.H0[c0] + b * 16384, p.H1[c1] + b * 16384, p.A, p.Wp[6], p.bias[6],
                         h1, u, p.RH1 + b * 16384, nullptr, nullptr, nullptr, nullptr, xsT, Hbuf);
    BAR();
    dc_stage<64, 128, 2>(b, n0, tid, nullptr, p.H0[c0] + b * 16384, p.RH1 + b * 16384, p.A, p.Wp[7], p.bias[7],
                         h1, u, p.H1[c1 ^ 1] + b * 16384, p.prW, p.prB, p.out + t * 256, p.XD, xsT, Hbuf);
    if (t != 11) BAR();
    c1 ^= 1;
  }
}

// ---------------- host ----------------
extern "C" void kernel_launch(void* const* d_in, const int* in_sizes, int n_in,
                              void* d_out, int out_size, void* d_ws, size_t ws_size,
                              hipStream_t stream)
{
  (void)in_sizes; (void)n_in; (void)out_size; (void)ws_size;
  KP p;
  p.enc_in = (const float*)d_in[0];
  p.sup0 = (const float*)d_in[2];
  p.sup1 = (const float*)d_in[3];
  p.Wsrc[0] = (const float*)d_in[4];  p.bias[0] = (const float*)d_in[5];
  p.Wsrc[1] = (const float*)d_in[6];  p.bias[1] = (const float*)d_in[7];
  p.Wsrc[2] = (const float*)d_in[8];  p.bias[2] = (const float*)d_in[9];
  p.Wsrc[3] = (const float*)d_in[10]; p.bias[3] = (const float*)d_in[11];
  p.Wsrc[4] = (const float*)d_in[12]; p.bias[4] = (const float*)d_in[13];
  p.Wsrc[5] = (const float*)d_in[14]; p.bias[5] = (const float*)d_in[15];
  p.Wsrc[6] = (const float*)d_in[16]; p.bias[6] = (const float*)d_in[17];
  p.Wsrc[7] = (const float*)d_in[18]; p.bias[7] = (const float*)d_in[19];
  p.prW = (const float*)d_in[20];
  p.prB = (const float*)d_in[21];
  p.out = (float*)d_out;

  char* ws = (char*)d_ws;
  size_t off = 0;
  auto carve = [&](size_t bytes) -> char* {
    char* qp = ws + off;
    off += (bytes + 255) & ~(size_t)255;
    return qp;
  };
  p.A = (unsigned short*)carve(4 * 65536 * 2);
  p.Wp[0] = (unsigned short*)carve(128 * 480 * 2);
  p.Wp[1] = (unsigned short*)carve(64 * 480 * 2);
  p.Wp[2] = (unsigned short*)carve(128 * 640 * 2);
  p.Wp[3] = (unsigned short*)carve(64 * 640 * 2);
  p.Wp[4] = (unsigned short*)carve(128 * 480 * 2);
  p.Wp[5] = (unsigned short*)carve(64 * 480 * 2);
  p.Wp[6] = (unsigned short*)carve(128 * 640 * 2);
  p.Wp[7] = (unsigned short*)carve(64 * 640 * 2);
  p.H0[0] = (unsigned short*)carve(64 * 64 * 256 * 2);
  p.H0[1] = (unsigned short*)carve(64 * 64 * 256 * 2);
  p.H1[0] = (unsigned short*)carve(64 * 64 * 256 * 2);
  p.H1[1] = (unsigned short*)carve(64 * 64 * 256 * 2);
  p.RH0 = (unsigned short*)carve(64 * 64 * 256 * 2);
  p.RH1 = (unsigned short*)carve(64 * 64 * 256 * 2);
  p.XD = (float*)carve(64 * 256 * 4);
  p.ctr = (unsigned*)carve(64 * 256);

  prep<<<dim3(512), dim3(256), 0, stream>>>(p);
  dcrnn_main<<<dim3(256), dim3(512), 0, stream>>>(p);
}